// Round 1
// baseline (222.556 us; speedup 1.0000x reference)
//
#include <hip/hip_runtime.h>

typedef _Float16 f16;
typedef _Float16 f16x8 __attribute__((ext_vector_type(8)));
typedef float    f32x16 __attribute__((ext_vector_type(16)));

#define NV      2000
#define RR      128
#define KM1     30
#define KKOUT   31          // K = KM1+1
#define NQ      900         // KM1*KM1
#define KTOT    16384       // RR*RR
#define COV_OFF 62000       // NV*KKOUT

// ---------------------------------------------------------------------------
// Kernel 1: permute Cov (3840x3840 fp32) -> B_ws f16 [q=0..1023][p=0..16383]
//   B[(k*30+l)*16384 + i*128 + j] = Cov[(i*30+k)*3840 + (j*30+l)],  q>=900 -> 0
// One block per Cov row (i,k); row staged in LDS (coalesced read), writes are
// 30 runs of 128 contiguous f16 (coalesced). Blocks 3840.. zero the pad rows.
// ---------------------------------------------------------------------------
__global__ void permute_cov_kernel(const float* __restrict__ cov,
                                   f16* __restrict__ Bp) {
    int blk = blockIdx.x;
    if (blk < 3840) {
        __shared__ float row[3840];
        const float* src = cov + (size_t)blk * 3840;
        for (int t = threadIdx.x; t < 3840; t += 256) row[t] = src[t];
        __syncthreads();
        int i = blk / 30;
        int k = blk - i * 30;
        f16* dstbase = Bp + (size_t)(k * 30) * KTOT + i * 128;
        for (int e = threadIdx.x; e < 3840; e += 256) {
            int l = e >> 7;          // 0..29
            int j = e & 127;         // 0..127
            dstbase[(size_t)l * KTOT + j] = (f16)row[j * 30 + l];
        }
    } else {
        int q = 900 + (blk - 3840);  // 900..1023
        uint4* dst = (uint4*)(Bp + (size_t)q * KTOT);
        uint4 z; z.x = z.y = z.z = z.w = 0u;
        for (int t = threadIdx.x; t < KTOT / 8; t += 256) dst[t] = z;
    }
}

// ---------------------------------------------------------------------------
// Kernel 2: initialize Post_cov_mats region: [v,0,0]=0.5, everything else 0.
// (GEMM atomically accumulates into the [1:,1:] sub-block afterwards.)
// ---------------------------------------------------------------------------
__global__ void cov_base_kernel(float* __restrict__ out_cov) {
    size_t idx = (size_t)blockIdx.x * 256 + threadIdx.x;
    const size_t total = (size_t)NV * KKOUT * KKOUT;
    if (idx >= total) return;
    unsigned rem = (unsigned)(idx % (KKOUT * KKOUT));
    out_cov[idx] = (rem == 0u) ? 0.5f : 0.0f;
}

// ---------------------------------------------------------------------------
// Kernel 3: Post_mean_coefs (2000 x 31), exact fp32.
//   col 0 = C_mu[v]; col c>=1: dot(X[v,:], W[:,c-1]) with W = mean.reshape(128,30)
// Thread map: v fastest across lanes -> Xi reads coalesced, W reads scalar.
// ---------------------------------------------------------------------------
__global__ void mean_kernel(const float* __restrict__ Xi,
                            const float* __restrict__ Wm,
                            const float* __restrict__ Cmu,
                            float* __restrict__ outm) {
    int tid = blockIdx.x * 256 + threadIdx.x;
    int c = tid >> 11;          // 0..30
    int v = tid & 2047;
    if (v >= NV || c >= KKOUT) return;
    if (c == 0) { outm[(size_t)v * KKOUT] = Cmu[v]; return; }
    float acc = 0.f;
    const float* w = Wm + (c - 1);
    #pragma unroll 8
    for (int i = 0; i < RR; ++i)
        acc = fmaf(Xi[i * NV + v], w[i * KM1], acc);
    outm[(size_t)v * KKOUT + c] = acc;
}

// ---------------------------------------------------------------------------
// Kernel 4: the GEMM.  out(2048pad x 1024pad) = G(2048 x 16384) @ B(16384 x 1024)
//   G[v, i*128+j] = X[v,i]*X[v,j], generated in registers (xj slices cached
//   for the whole j-cycle; only xi changes per 128-k stage -> 4 pk_mul/frag).
// BM=BN=128, 4 waves in 2x2 of 64x64, mfma_f32_32x32x16_f16, K-split=4 with
// fp32 atomicAdd epilogue into the (k+1,l+1) positions of Post_cov_mats.
// grid.x = N-tile so each XCD's L2 sees one 4MB B slice.
// ---------------------------------------------------------------------------
__launch_bounds__(256, 2)
__global__ void gemm_cov_kernel(const float* __restrict__ Xi,
                                const f16* __restrict__ Bp,
                                float* __restrict__ out_cov) {
    __shared__ __align__(16) f16 Xh[128 * 136];   // X[v][r], stride 136
    __shared__ __align__(16) f16 Bl[128 * 136];   // B[n][k],  stride 136

    const int tid  = threadIdx.x;
    const int lane = tid & 63;
    const int wave = tid >> 6;
    const int wm = wave & 1, wn = wave >> 1;
    const int l31 = lane & 31, kq = lane >> 5;    // kq in {0,1}
    const int q0 = blockIdx.x * 128;
    const int v0 = blockIdx.y * 128;
    const int kz = blockIdx.z;                    // 0..3

    // ---- stage X tile: Xh[v][r] = Xi[r*NV + v0+v] (f16), zero-pad v>=NV ----
    for (int e = tid; e < 128 * 128; e += 256) {
        int r = e >> 7, v = e & 127;
        float x = (v0 + v < NV) ? Xi[r * NV + v0 + v] : 0.f;
        Xh[v * 136 + r] = (f16)x;
    }
    __syncthreads();

    // ---- preload xj fragment slices (whole 128-j cycle) into registers ----
    const int vb0 = wm * 64 + l31;                // fm=0 row for this lane
    f16x8 xj[2][8];
    #pragma unroll
    for (int fm = 0; fm < 2; ++fm)
        #pragma unroll
        for (int s = 0; s < 8; ++s)
            xj[fm][s] = *(const f16x8*)&Xh[(vb0 + fm * 32) * 136 + s * 16 + kq * 8];

    f32x16 acc[2][2] = {};

    const int i0beg = kz * 32;
    for (int ii = 0; ii < 32; ++ii) {
        const int i0 = i0beg + ii;                // global i index, 0..127
        __syncthreads();                          // Bl safe to overwrite
        // ---- stage B tile: 128 q-rows x 128 p-cols (f16) ----
        {
            const int qrow  = tid >> 4;           // 0..15
            const int chunk = tid & 15;           // 0..15, 8 f16 each
            const f16* gsrc = Bp + (size_t)(q0 + qrow) * KTOT + i0 * 128 + chunk * 8;
            f16* ldst = Bl + qrow * 136 + chunk * 8;
            #pragma unroll
            for (int pass = 0; pass < 8; ++pass)
                *(uint4*)(ldst + pass * 16 * 136) =
                    *(const uint4*)(gsrc + (size_t)pass * 16 * KTOT);
        }
        // xi for this stage (constant over the stage)
        f16 xia = Xh[vb0 * 136 + i0];
        f16 xib = Xh[(vb0 + 32) * 136 + i0];
        f16x8 xs0, xs1;
        #pragma unroll
        for (int d = 0; d < 8; ++d) { xs0[d] = xia; xs1[d] = xib; }
        __syncthreads();
        // ---- 8 k16-steps over this stage's 128 k values ----
        #pragma unroll
        for (int s = 0; s < 8; ++s) {
            f16x8 a0 = xs0 * xj[0][s];            // v_pk_mul_f16 x4
            f16x8 a1 = xs1 * xj[1][s];
            f16x8 b0 = *(const f16x8*)&Bl[(wn * 64 + l31) * 136 + s * 16 + kq * 8];
            f16x8 b1 = *(const f16x8*)&Bl[(wn * 64 + 32 + l31) * 136 + s * 16 + kq * 8];
            acc[0][0] = __builtin_amdgcn_mfma_f32_32x32x16_f16(a0, b0, acc[0][0], 0, 0, 0);
            acc[0][1] = __builtin_amdgcn_mfma_f32_32x32x16_f16(a0, b1, acc[0][1], 0, 0, 0);
            acc[1][0] = __builtin_amdgcn_mfma_f32_32x32x16_f16(a1, b0, acc[1][0], 0, 0, 0);
            acc[1][1] = __builtin_amdgcn_mfma_f32_32x32x16_f16(a1, b1, acc[1][1], 0, 0, 0);
        }
    }

    // ---- epilogue: C/D layout col=lane&31, row=(reg&3)+8*(reg>>2)+4*kq ----
    #pragma unroll
    for (int fn = 0; fn < 2; ++fn) {
        int q = q0 + wn * 64 + fn * 32 + l31;
        if (q >= NQ) continue;
        int k = q / 30;
        int l = q - k * 30;
        float* colbase = out_cov + (size_t)(k + 1) * KKOUT + (l + 1);
        #pragma unroll
        for (int fm = 0; fm < 2; ++fm) {
            int vrow0 = v0 + wm * 64 + fm * 32 + 4 * kq;
            #pragma unroll
            for (int reg = 0; reg < 16; ++reg) {
                int vrow = vrow0 + (reg & 3) + 8 * (reg >> 2);
                if (vrow < NV)
                    atomicAdd(colbase + (size_t)vrow * (KKOUT * KKOUT),
                              acc[fm][fn][reg]);
            }
        }
    }
}

// ---------------------------------------------------------------------------
extern "C" void kernel_launch(void* const* d_in, const int* in_sizes, int n_in,
                              void* d_out, int out_size, void* d_ws, size_t ws_size,
                              hipStream_t stream) {
    const float* Xi  = (const float*)d_in[0];   // (128, 2000)
    const float* Wm  = (const float*)d_in[1];   // (3840, 1)
    const float* Cov = (const float*)d_in[2];   // (3840, 3840)
    const float* Cmu = (const float*)d_in[3];   // (2000, 1)
    float* out      = (float*)d_out;
    float* out_mean = out;                       // (2000, 31)
    float* out_cov  = out + COV_OFF;             // (2000, 31, 31)
    f16*   Bp       = (f16*)d_ws;                // needs 1024*16384*2 = 33.5 MB

    permute_cov_kernel<<<3964, 256, 0, stream>>>(Cov, Bp);
    cov_base_kernel<<<(NV * KKOUT * KKOUT + 255) / 256, 256, 0, stream>>>(out_cov);
    mean_kernel<<<(2048 * KKOUT) / 256, 256, 0, stream>>>(Xi, Wm, Cmu, out_mean);
    gemm_cov_kernel<<<dim3(8, 16, 4), 256, 0, stream>>>(Xi, Bp, out_cov);
}

// Round 2
// 187.651 us; speedup vs baseline: 1.1860x; 1.1860x over previous
//
#include <hip/hip_runtime.h>

typedef _Float16 f16;
typedef _Float16 f16x8 __attribute__((ext_vector_type(8)));
typedef float    f32x16 __attribute__((ext_vector_type(16)));

#define NV      2000
#define RR      128
#define KM1     30
#define KKOUT   31
#define NQ      900          // KM1*KM1
#define QQ      961          // KKOUT*KKOUT
#define COV_OFF 62000        // NV*KKOUT

// ws layout:
//   B2  at byte 0        : 30 qt2-tiles x 128 i x 8 s x 1024 B  = 31,457,280 B
//       element: lane(kq,l31) slot holds B[q=qt2*32+l31][j=s*16+kq*8+d], d=0..7 (f16)
//   Xh  at byte 31457280 : f16 X^T [v=0..2047][r=0..127] = 524,288 B
#define B2_BYTES 31457280

// ---------------------------------------------------------------------------
// Xi (128 x 2000 fp32) -> Xh f16 [v][r], zero-padded v >= 2000.
// ---------------------------------------------------------------------------
__global__ void xcast_kernel(const float* __restrict__ Xi, f16* __restrict__ Xh) {
    int t = blockIdx.x * 256 + threadIdx.x;      // 2048*16 threads
    int v = t & 2047, rc = t >> 11;              // rc 0..15
    f16 vals[8];
#pragma unroll
    for (int d = 0; d < 8; ++d) {
        float x = (v < NV) ? Xi[(rc * 8 + d) * NV + v] : 0.f;
        vals[d] = (f16)x;
    }
    *(uint4*)(Xh + (size_t)v * 128 + rc * 8) = *(uint4*)vals;
}

// ---------------------------------------------------------------------------
// Cov (3840x3840 fp32) -> B2 fragment-tiled f16.
// One block per Cov row (i,k). Thread (s,kq,ql): reads 8 floats
// Cov[i*30+k][(s*16+kq*8+d)*30 + ql], writes one 16B chunk of B2.
// q rows 900..959 are read by the GEMM but their outputs are discarded, so
// the 0xAA ws poison there is harmless (finite f16); no zero-fill needed.
// ---------------------------------------------------------------------------
__global__ void permute2_kernel(const float* __restrict__ cov, f16* __restrict__ B2) {
    int blk = blockIdx.x;                        // i*30 + k
    int i = blk / 30, k = blk - i * 30;
    int t = threadIdx.x;                         // 512
    int s = t >> 6, kq = (t >> 5) & 1, ql = t & 31;
    if (ql >= 30) return;
    int q = 30 * k + ql;
    int qt2 = q >> 5, l31 = q & 31;
    const float* src = cov + (size_t)blk * 3840 + (s * 16 + kq * 8) * 30 + ql;
    f16 vals[8];
#pragma unroll
    for (int d = 0; d < 8; ++d) vals[d] = (f16)src[d * 30];
    f16* dst = B2 + (((size_t)qt2 * 128 + i) * 8 + s) * 512 + kq * 256 + l31 * 8;
    *(uint4*)dst = *(uint4*)vals;
}

// ---------------------------------------------------------------------------
// Zero the whole Post_cov_mats region (1,922,000 floats, /4 exact).
// ---------------------------------------------------------------------------
__global__ void zero_cov_kernel(float* __restrict__ oc) {
    size_t idx = ((size_t)blockIdx.x * 256 + threadIdx.x) * 4;
    if (idx < (size_t)NV * QQ) {
        float4 z = {0.f, 0.f, 0.f, 0.f};
        *(float4*)(oc + idx) = z;
    }
}

// ---------------------------------------------------------------------------
// Post_mean_coefs (2000 x 31) exact fp32; c==0 also plants cov[v,0,0]=0.5
// (runs after zero_cov on the stream).
// ---------------------------------------------------------------------------
__global__ void mean_kernel(const float* __restrict__ Xi,
                            const float* __restrict__ Wm,
                            const float* __restrict__ Cmu,
                            float* __restrict__ outm,
                            float* __restrict__ oc) {
    int tid = blockIdx.x * 256 + threadIdx.x;
    int c = tid >> 11;
    int v = tid & 2047;
    if (v >= NV || c >= KKOUT) return;
    if (c == 0) {
        outm[(size_t)v * KKOUT] = Cmu[v];
        oc[(size_t)v * QQ] = 0.5f;
        return;
    }
    float acc = 0.f;
    const float* w = Wm + (c - 1);
#pragma unroll 8
    for (int i = 0; i < RR; ++i)
        acc = fmaf(Xi[i * NV + v], w[i * KM1], acc);
    outm[(size_t)v * KKOUT + c] = acc;
}

// ---------------------------------------------------------------------------
// GEMM: out(2048 x 960used) = G(2048 x 16384) @ B(16384 x 960), no LDS, no
// barriers. BM=128, BN=64, KZ=2; 4 waves of 64rows x 32cols (wm,wn).
// A generated in registers (xj cached for whole kernel, xi per 8-stage group);
// B streamed global->reg, fragment-tiled, one-stage-ahead double buffer.
// Epilogue: fp32 atomicAdd into (k+1,l+1) slots (KZ=2 partial sums).
// ---------------------------------------------------------------------------
__launch_bounds__(256, 2)
__global__ void gemm_cov2_kernel(const f16* __restrict__ B2,
                                 const f16* __restrict__ Xh,
                                 float* __restrict__ out_cov) {
    const int q0 = blockIdx.x * 64;
    if (q0 >= NQ) return;                        // dead tile (x==15... only x<=14 live)
    const int tid  = threadIdx.x;
    const int lane = tid & 63;
    const int wave = tid >> 6;
    const int wm = wave & 1, wn = wave >> 1;
    const int l31 = lane & 31, kq = lane >> 5;
    const int v0 = blockIdx.y * 128;
    const int kz = blockIdx.z;
    const int qt2 = (q0 >> 5) + wn;

    const int vr0 = v0 + wm * 64 + l31;          // fm=0 output row for this lane
    const f16* xrow0 = Xh + (size_t)vr0 * 128;
    const f16* xrow1 = xrow0 + 32 * 128;         // fm=1 row

    // xj[fm][s]: x[v_fm, j], j = s*16 + kq*8 .. +7   (held all kernel: 64 VGPR)
    f16x8 xj[2][8];
#pragma unroll
    for (int s = 0; s < 8; ++s) {
        xj[0][s] = *(const f16x8*)(xrow0 + s * 16 + kq * 8);
        xj[1][s] = *(const f16x8*)(xrow1 + s * 16 + kq * 8);
    }

    const int ibeg = kz * 64;                    // this block's 64 i-stages
    const f16* bptr = B2 + ((size_t)qt2 * 128 + ibeg) * 4096 + lane * 8;

    f32x16 acc[2] = {};
    f16x8 bbuf[2][8];
#pragma unroll
    for (int s = 0; s < 8; ++s)                  // preload stage 0
        bbuf[0][s] = *(const f16x8*)(bptr + s * 512);

    for (int g = 0; g < 8; ++g) {
        f16x8 xi0 = *(const f16x8*)(xrow0 + ibeg + g * 8);
        f16x8 xi1 = *(const f16x8*)(xrow1 + ibeg + g * 8);
#pragma unroll
        for (int t = 0; t < 8; ++t) {
            const int st = g * 8 + t;            // stage 0..63
            const int p  = t & 1;                // bbuf holding stage st
            // prefetch stage st+1 (clamped; independent of compute below)
            const f16* nb = bptr + (size_t)(st < 63 ? st + 1 : 63) * 4096;
#pragma unroll
            for (int s = 0; s < 8; ++s)
                bbuf[p ^ 1][s] = *(const f16x8*)(nb + s * 512);
            // broadcast xi for this stage
            f16 a0 = xi0[t], a1 = xi1[t];
            f16x8 xs0, xs1;
#pragma unroll
            for (int d = 0; d < 8; ++d) { xs0[d] = a0; xs1[d] = a1; }
#pragma unroll
            for (int s = 0; s < 8; ++s) {
                f16x8 af0 = xs0 * xj[0][s];
                f16x8 af1 = xs1 * xj[1][s];
                acc[0] = __builtin_amdgcn_mfma_f32_32x32x16_f16(af0, bbuf[p][s], acc[0], 0, 0, 0);
                acc[1] = __builtin_amdgcn_mfma_f32_32x32x16_f16(af1, bbuf[p][s], acc[1], 0, 0, 0);
            }
        }
    }

    // epilogue: C/D layout col=lane&31 (q), row=4*kq+(reg&3)+8*(reg>>2) (v)
    const int q = q0 + wn * 32 + l31;
    if (q >= NQ) return;
    const int kk = q / 30, ll = q - kk * 30;
    float* cb = out_cov + (kk + 1) * KKOUT + (ll + 1);
#pragma unroll
    for (int fm = 0; fm < 2; ++fm) {
        int vb = v0 + wm * 64 + fm * 32 + 4 * kq;
#pragma unroll
        for (int r = 0; r < 16; ++r) {
            int v = vb + (r & 3) + 8 * (r >> 2);
            if (v < NV) atomicAdd(cb + (size_t)v * QQ, acc[fm][r]);
        }
    }
}

// ---------------------------------------------------------------------------
extern "C" void kernel_launch(void* const* d_in, const int* in_sizes, int n_in,
                              void* d_out, int out_size, void* d_ws, size_t ws_size,
                              hipStream_t stream) {
    const float* Xi  = (const float*)d_in[0];   // (128, 2000)
    const float* Wm  = (const float*)d_in[1];   // (3840, 1)
    const float* Cov = (const float*)d_in[2];   // (3840, 3840)
    const float* Cmu = (const float*)d_in[3];   // (2000, 1)
    float* out      = (float*)d_out;
    float* out_mean = out;                       // (2000, 31)
    float* out_cov  = out + COV_OFF;             // (2000, 31, 31)
    f16* B2 = (f16*)d_ws;
    f16* Xh = (f16*)((char*)d_ws + B2_BYTES);

    xcast_kernel   <<<128, 256, 0, stream>>>(Xi, Xh);
    permute2_kernel<<<3840, 512, 0, stream>>>(Cov, B2);
    zero_cov_kernel<<<((NV * QQ / 4) + 255) / 256, 256, 0, stream>>>(out_cov);
    mean_kernel    <<<(2048 * KKOUT) / 256, 256, 0, stream>>>(Xi, Wm, Cmu, out_mean, out_cov);
    gemm_cov2_kernel<<<dim3(16, 16, 2), 256, 0, stream>>>(B2, Xh, out_cov);
}